// Round 10
// baseline (311.223 us; speedup 1.0000x reference)
//
#include <hip/hip_runtime.h>
#include <hip/hip_bf16.h>

// KNN_itc: out[b][n] = sum over support descriptors m (441) of top-3 (over 441
// query descriptors) cosine similarities, C=640, bf16 MFMA.
//
// R15 (vs R14 FAILED B-LDS=156us, vs R12/R13 best gemm=113.6us):
//  - R14 post-mortem: cutting L2 traffic 27% made gemm SLOWER (L2 BW achieved
//    fell 20.4 -> 10.8 TB/s) => R12 is NOT L2-BW-bound; barriers/lockstep are
//    the poison (R6 20bar=135, R14 4bar=156, R12 0bar=113). Revert to R12's
//    free-running all-register skeleton.
//  - R12 limiter theory: distance-1 reg double-buffer covers only ~136-270cy
//    vs ~200-900cy load latency => latency-bound (MfmaUtil 37 + VALUBusy 32,
//    low BW). R15: A triple-buffered (prefetch distance 2; A = 64% of bytes),
//    B double. Fully-unrolled kt loop -> all set indices static (rule #20).
//    Regs: sets 132 + acc 112 ~ 248 <= 256 cap of (256,2). Tripwire:
//    WRITE_SIZE must stay 82KB.
//  - Epilogue: row<HW clamp hoisted to the only static case (r==6), removes
//    ~100 cndmasks.
//  - prep UNCHANGED from R13 (fused norm+pack, 2 dispatches; non-gemm ~145us
//    is harness-fixed reset train, refractory to prep changes).

#define B_IMGS 75
#define N_CLS  5
#define C_DIM  640
#define HW     441
#define HWP    448
#define NKT    20            // 640 / 32 k-chunks
#define NRB    28            // 448 / 16 row-blocks per image
#define CHUNK  512           // 16 rows x 32 k elems = 1 KiB

typedef __attribute__((ext_vector_type(8))) short  short8;   // 8 x bf16
typedef __attribute__((ext_vector_type(4))) float  float4v;  // MFMA acc

__device__ __forceinline__ void ins3(float& t0, float& t1, float& t2, float v) {
    float m  = fminf(t0, v);
    t0 = fmaxf(t0, v);
    float m2 = fminf(t1, m);
    t1 = fmaxf(t1, m);
    t2 = fmaxf(t2, m2);
}

// ---- fused prep: sumsq + normalize + bf16 + fragment-linear pack ----
// block=(img 0..79, h0 0..6); 560 blocks x 256 thr
// chunk layout: elem(row=r16, k32) at oct*128 + r16*8 + (k32&7), oct=k32>>3
//   -> gemm lane l reads elems [l*8, l*8+8): row=l&15, k32=(l>>4)*8+j (MFMA frag)
__global__ __launch_bounds__(256)
void prep_kernel(const float* __restrict__ q, const float* __restrict__ S,
                 __hip_bfloat16* __restrict__ qn2, __hip_bfloat16* __restrict__ sn2,
                 float* __restrict__ out) {
    __shared__ float part[4][64];
    __shared__ float inv[64];

    int bid = blockIdx.x;
    // zero the output accumulator (replaces the hipMemsetAsync dispatch);
    // gemm is a later dispatch on the same stream -> ordering is safe.
    if (bid == 0) {
        for (int i = threadIdx.x; i < B_IMGS * N_CLS; i += 256) out[i] = 0.f;
    }

    int img = bid / 7;               // 0..79 (0..74 = q, 75..79 = S)
    int h0  = bid % 7;
    const float* src; __hip_bfloat16* dst;
    if (img < B_IMGS) {
        src = q + (size_t)img * C_DIM * HW;
        dst = qn2 + (size_t)img * NRB * NKT * CHUNK;
    } else {
        src = S + (size_t)(img - B_IMGS) * C_DIM * HW;
        dst = sn2 + (size_t)(img - B_IMGS) * NRB * NKT * CHUNK;
    }
    int t  = threadIdx.x;
    int hl = t & 63;
    int p  = t >> 6;                 // wave id / 160-channel slice
    int hw = h0 * 64 + hl;
    int hwc = (hw < HW) ? hw : (HW - 1);

    // ---- pass 1: sum of squares over C (coalesced, 16-deep batches) ----
    float ss = 0.f;
    for (int c0 = p * 160; c0 < (p + 1) * 160; c0 += 16) {
        float v[16];
#pragma unroll
        for (int j = 0; j < 16; ++j) v[j] = src[(size_t)(c0 + j) * HW + hwc];
#pragma unroll
        for (int j = 0; j < 16; ++j) ss += v[j] * v[j];
    }
    part[p][hl] = ss;
    __syncthreads();
    if (t < 64) {
        float tot = part[0][t] + part[1][t] + part[2][t] + part[3][t];
        // pad rows (hw>=441) -> 0 so packed pad descriptors are zeros
        inv[t] = (h0 * 64 + t < HW) ? rsqrtf(tot) : 0.f;
    }
    __syncthreads();

    // ---- pass 2: L2/L3-hot re-read, scale, pack in registers, store ----
    // wave p owns chunk rb = h0*4+p; lane tl writes bytes [tl*16, tl*16+16)
    int tl  = hl;
    int row = tl & 15;
    int oct = tl >> 4;
    int rb  = h0 * 4 + p;
    int hw2 = h0 * 64 + p * 16 + row;
    int hw2c = (hw2 < HW) ? hw2 : (HW - 1);
    float iv = inv[p * 16 + row];    // 0 for pad rows
    const float* s2 = src + hw2c;
#pragma unroll 2
    for (int kt = 0; kt < NKT; ++kt) {
        float v[8];
#pragma unroll
        for (int j = 0; j < 8; ++j)
            v[j] = s2[(size_t)(kt * 32 + oct * 8 + j) * HW];
        short8 o;
#pragma unroll
        for (int j = 0; j < 8; ++j) {
            __hip_bfloat16 h = __float2bfloat16(v[j] * iv);
            o[j] = *(short*)&h;
        }
        *(short8*)(dst + ((size_t)rb * NKT + kt) * CHUNK + tl * 8) = o;
    }
}

// ---- gemm + fused top-3: barrier-free, all-register, A prefetch depth 2 ----
#define LOADA(aS, kt)                                                           \
    {                                                                           \
        _Pragma("unroll")                                                       \
        for (int r = 0; r < 7; ++r)                                             \
            aS[r] = *(const short8*)(pA + ((size_t)(r * 4 + w) * NKT + (kt)) * CHUNK); \
    }

#define LOADB(bS, kt)                                                           \
    {                                                                           \
        _Pragma("unroll")                                                       \
        for (int j = 0; j < 4; ++j)                                             \
            bS[j] = *(const short8*)(pB + ((size_t)j * NKT + (kt)) * CHUNK);    \
    }

#define MFMASET(aS, bS)                                                         \
    {                                                                           \
        _Pragma("unroll")                                                       \
        for (int r = 0; r < 7; ++r)                                             \
            _Pragma("unroll")                                                   \
            for (int j = 0; j < 4; ++j)                                         \
                acc[r][j] = __builtin_amdgcn_mfma_f32_16x16x32_bf16(            \
                    aS[r], bS[j], acc[r][j], 0, 0, 0);                          \
    }

__global__ __launch_bounds__(256, 2)
void gemm_top3_kernel(const __hip_bfloat16* __restrict__ qn2,
                      const __hip_bfloat16* __restrict__ sn2,
                      float* __restrict__ out) {
    __shared__ float mrg[4][64][3];

    // XCD-grouping swizzle: all 35 (n,mt) blocks of image b on one XCD
    int id  = blockIdx.x;
    int xcd = id & 7;
    int j8  = id >> 3;
    int b   = (j8 / 35) * 8 + xcd;
    if (b >= B_IMGS) return;
    int inner = j8 % 35;
    int n  = inner / 7;
    int mt = inner % 7;

    int tid  = threadIdx.x;
    int w    = tid >> 6;
    int lane = tid & 63;
    int c16  = lane & 15;
    int quad = lane >> 4;

    // fragment base: lane l owns bytes [l*16, l*16+16) of each 1KiB chunk
    const __hip_bfloat16* pA = qn2 + (size_t)b * NRB * NKT * CHUNK + lane * 8;
    const __hip_bfloat16* pB = sn2 + ((size_t)n * NRB + mt * 4) * NKT * CHUNK + lane * 8;

    float4v acc[7][4];
#pragma unroll
    for (int r = 0; r < 7; ++r)
#pragma unroll
        for (int j = 0; j < 4; ++j)
            acc[r][j] = (float4v){0.f, 0.f, 0.f, 0.f};

    // A: 3 sets (prefetch distance 2); B: 2 sets (distance 1).
    // Fully-unrolled kt loop -> all indices compile-time (stay in registers).
    short8 as[3][7], bs[2][4];
    LOADA(as[0], 0)  LOADB(bs[0], 0)
    LOADA(as[1], 1)  LOADB(bs[1], 1)
    LOADA(as[2], 2)
#pragma unroll
    for (int kt = 0; kt < NKT; ++kt) {
        MFMASET(as[kt % 3], bs[kt & 1])
        if (kt + 3 < NKT) LOADA(as[kt % 3], kt + 3)       // slot just freed
        if (kt + 2 < NKT) LOADB(bs[kt & 1], kt + 2)
    }

    // ---- in-register top-3 over this wave's 112 rows, per owned column ----
    // rows r*64 + w*16 + quad*4 + g; only r==6 can exceed HW=441 (static).
    float T0[4], T1[4], T2[4];
#pragma unroll
    for (int j = 0; j < 4; ++j) { T0[j] = -1e30f; T1[j] = -1e30f; T2[j] = -1e30f; }
#pragma unroll
    for (int r = 0; r < 7; ++r)
#pragma unroll
        for (int j = 0; j < 4; ++j)
#pragma unroll
            for (int g = 0; g < 4; ++g) {
                float v = acc[r][j][g];
                if (r == 6) {
                    int row = 384 + w * 16 + quad * 4 + g;
                    if (row >= HW) v = -1e30f;
                }
                ins3(T0[j], T1[j], T2[j], v);
            }

    // quad-butterfly merge (rows spread over lane bits 4,5)
#pragma unroll
    for (int j = 0; j < 4; ++j) {
#pragma unroll
        for (int d = 16; d <= 32; d <<= 1) {
            float o0 = __shfl_xor(T0[j], d, 64);
            float o1 = __shfl_xor(T1[j], d, 64);
            float o2 = __shfl_xor(T2[j], d, 64);
            ins3(T0[j], T1[j], T2[j], o0);
            ins3(T0[j], T1[j], T2[j], o1);
            ins3(T0[j], T1[j], T2[j], o2);
        }
    }

    // cross-wave merge via LDS
    if (quad == 0) {
#pragma unroll
        for (int j = 0; j < 4; ++j) {
            mrg[w][j * 16 + c16][0] = T0[j];
            mrg[w][j * 16 + c16][1] = T1[j];
            mrg[w][j * 16 + c16][2] = T2[j];
        }
    }
    __syncthreads();
    if (tid < 64) {
        int col = tid;
        float t0 = mrg[0][col][0], t1 = mrg[0][col][1], t2 = mrg[0][col][2];
#pragma unroll
        for (int ww = 1; ww < 4; ++ww) {
            ins3(t0, t1, t2, mrg[ww][col][0]);
            ins3(t0, t1, t2, mrg[ww][col][1]);
            ins3(t0, t1, t2, mrg[ww][col][2]);
        }
        float s = (mt * 64 + col < HW) ? (t0 + t1 + t2) : 0.f;
#pragma unroll
        for (int d = 32; d >= 1; d >>= 1) s += __shfl_xor(s, d, 64);
        if (tid == 0) atomicAdd(&out[b * N_CLS + n], s);
    }
}

extern "C" void kernel_launch(void* const* d_in, const int* in_sizes, int n_in,
                              void* d_out, int out_size, void* d_ws, size_t ws_size,
                              hipStream_t stream) {
    const float* q = (const float*)d_in[0];
    const float* S = (const float*)d_in[1];
    float* out = (float*)d_out;

    char* ws = (char*)d_ws;
    size_t off = 0;
    __hip_bfloat16* qn2 = (__hip_bfloat16*)(ws + off);
    off += (size_t)B_IMGS * NRB * NKT * CHUNK * 2;  off = (off + 255) & ~(size_t)255;
    __hip_bfloat16* sn2 = (__hip_bfloat16*)(ws + off);

    // 2 dispatches total: fused prep (also zeroes out) -> gemm
    prep_kernel<<<dim3(80 * 7), dim3(256), 0, stream>>>(q, S, qn2, sn2, out);
    // 8 XCD groups x 350 slots (35 blocks/image); b>=75 slots exit immediately
    gemm_top3_kernel<<<dim3(8 * 350), dim3(256), 0, stream>>>(qn2, sn2, out);
}

// Round 11
// 255.868 us; speedup vs baseline: 1.2163x; 1.2163x over previous
//
#include <hip/hip_runtime.h>
#include <hip/hip_bf16.h>

// KNN_itc: out[b][n] = sum over support descriptors m (441) of top-3 (over 441
// query descriptors) cosine similarities, C=640, bf16 MFMA.
//
// R16 (vs R15 FAILED reg-cap=162us, vs R12/R13 best gemm=113.6us):
//  - R15 post-mortem: VGPR_Count=128 == cap (256 unified - 112 AGPR acc = 144
//    arch; 164 buffer regs didn't fit) -> allocator pinned, scheduler
//    serialized (VALUBusy 32->16.7). HARD WALL: register prefetch depth <=
//    ~9KB in flight vs 11KB consumed/kt. Deep pipelines need LDS, and every
//    LDS/barrier variant lost (R6 135, R7 159, R8 165, R14 156).
//  - R16 = R12 skeleton + three register-safe micro-levers:
//    (1) rolling per-rb A refill: as[kt&1][r] reloaded for kt+2 right after
//        its last MFMA read (WAR-pinned position, zero extra regs; A coverage
//        ~272 -> ~400+cy).
//    (2) B distance-3 (3 sets, +16 regs; buffers 104 total -> VGPR ~130 < 144).
//    (3) s_setprio(1) around MFMA quads: barrier-free independent waves =
//        the attn-like regime where setprio measured +4-7% (m191).
//    plus static r==6 epilogue clamp (from R15, harmless).
//  - prep UNCHANGED from R13 (fused norm+pack, 2 dispatches; non-gemm ~142us
//    is harness-fixed reset train, invariant across 6 structures).

#define B_IMGS 75
#define N_CLS  5
#define C_DIM  640
#define HW     441
#define HWP    448
#define NKT    20            // 640 / 32 k-chunks
#define NRB    28            // 448 / 16 row-blocks per image
#define CHUNK  512           // 16 rows x 32 k elems = 1 KiB

typedef __attribute__((ext_vector_type(8))) short  short8;   // 8 x bf16
typedef __attribute__((ext_vector_type(4))) float  float4v;  // MFMA acc

__device__ __forceinline__ void ins3(float& t0, float& t1, float& t2, float v) {
    float m  = fminf(t0, v);
    t0 = fmaxf(t0, v);
    float m2 = fminf(t1, m);
    t1 = fmaxf(t1, m);
    t2 = fmaxf(t2, m2);
}

// ---- fused prep: sumsq + normalize + bf16 + fragment-linear pack ----
// block=(img 0..79, h0 0..6); 560 blocks x 256 thr
// chunk layout: elem(row=r16, k32) at oct*128 + r16*8 + (k32&7), oct=k32>>3
//   -> gemm lane l reads elems [l*8, l*8+8): row=l&15, k32=(l>>4)*8+j (MFMA frag)
__global__ __launch_bounds__(256)
void prep_kernel(const float* __restrict__ q, const float* __restrict__ S,
                 __hip_bfloat16* __restrict__ qn2, __hip_bfloat16* __restrict__ sn2,
                 float* __restrict__ out) {
    __shared__ float part[4][64];
    __shared__ float inv[64];

    int bid = blockIdx.x;
    // zero the output accumulator (replaces the hipMemsetAsync dispatch);
    // gemm is a later dispatch on the same stream -> ordering is safe.
    if (bid == 0) {
        for (int i = threadIdx.x; i < B_IMGS * N_CLS; i += 256) out[i] = 0.f;
    }

    int img = bid / 7;               // 0..79 (0..74 = q, 75..79 = S)
    int h0  = bid % 7;
    const float* src; __hip_bfloat16* dst;
    if (img < B_IMGS) {
        src = q + (size_t)img * C_DIM * HW;
        dst = qn2 + (size_t)img * NRB * NKT * CHUNK;
    } else {
        src = S + (size_t)(img - B_IMGS) * C_DIM * HW;
        dst = sn2 + (size_t)(img - B_IMGS) * NRB * NKT * CHUNK;
    }
    int t  = threadIdx.x;
    int hl = t & 63;
    int p  = t >> 6;                 // wave id / 160-channel slice
    int hw = h0 * 64 + hl;
    int hwc = (hw < HW) ? hw : (HW - 1);

    // ---- pass 1: sum of squares over C (coalesced, 16-deep batches) ----
    float ss = 0.f;
    for (int c0 = p * 160; c0 < (p + 1) * 160; c0 += 16) {
        float v[16];
#pragma unroll
        for (int j = 0; j < 16; ++j) v[j] = src[(size_t)(c0 + j) * HW + hwc];
#pragma unroll
        for (int j = 0; j < 16; ++j) ss += v[j] * v[j];
    }
    part[p][hl] = ss;
    __syncthreads();
    if (t < 64) {
        float tot = part[0][t] + part[1][t] + part[2][t] + part[3][t];
        // pad rows (hw>=441) -> 0 so packed pad descriptors are zeros
        inv[t] = (h0 * 64 + t < HW) ? rsqrtf(tot) : 0.f;
    }
    __syncthreads();

    // ---- pass 2: L2/L3-hot re-read, scale, pack in registers, store ----
    // wave p owns chunk rb = h0*4+p; lane tl writes bytes [tl*16, tl*16+16)
    int tl  = hl;
    int row = tl & 15;
    int oct = tl >> 4;
    int rb  = h0 * 4 + p;
    int hw2 = h0 * 64 + p * 16 + row;
    int hw2c = (hw2 < HW) ? hw2 : (HW - 1);
    float iv = inv[p * 16 + row];    // 0 for pad rows
    const float* s2 = src + hw2c;
#pragma unroll 2
    for (int kt = 0; kt < NKT; ++kt) {
        float v[8];
#pragma unroll
        for (int j = 0; j < 8; ++j)
            v[j] = s2[(size_t)(kt * 32 + oct * 8 + j) * HW];
        short8 o;
#pragma unroll
        for (int j = 0; j < 8; ++j) {
            __hip_bfloat16 h = __float2bfloat16(v[j] * iv);
            o[j] = *(short*)&h;
        }
        *(short8*)(dst + ((size_t)rb * NKT + kt) * CHUNK + tl * 8) = o;
    }
}

// ---- gemm + fused top-3: barrier-free all-register; rolling A, B dist-3 ----
#define LOADA_RB(dstv, r, kt)                                                   \
    dstv = *(const short8*)(pA + ((size_t)((r) * 4 + w) * NKT + (kt)) * CHUNK);

#define LOADB(bS, kt)                                                           \
    {                                                                           \
        _Pragma("unroll")                                                       \
        for (int j = 0; j < 4; ++j)                                             \
            bS[j] = *(const short8*)(pB + ((size_t)j * NKT + (kt)) * CHUNK);    \
    }

__global__ __launch_bounds__(256, 2)
void gemm_top3_kernel(const __hip_bfloat16* __restrict__ qn2,
                      const __hip_bfloat16* __restrict__ sn2,
                      float* __restrict__ out) {
    __shared__ float mrg[4][64][3];

    // XCD-grouping swizzle: all 35 (n,mt) blocks of image b on one XCD
    int id  = blockIdx.x;
    int xcd = id & 7;
    int j8  = id >> 3;
    int b   = (j8 / 35) * 8 + xcd;
    if (b >= B_IMGS) return;
    int inner = j8 % 35;
    int n  = inner / 7;
    int mt = inner % 7;

    int tid  = threadIdx.x;
    int w    = tid >> 6;
    int lane = tid & 63;
    int c16  = lane & 15;
    int quad = lane >> 4;

    // fragment base: lane l owns bytes [l*16, l*16+16) of each 1KiB chunk
    const __hip_bfloat16* pA = qn2 + (size_t)b * NRB * NKT * CHUNK + lane * 8;
    const __hip_bfloat16* pB = sn2 + ((size_t)n * NRB + mt * 4) * NKT * CHUNK + lane * 8;

    float4v acc[7][4];
#pragma unroll
    for (int r = 0; r < 7; ++r)
#pragma unroll
        for (int j = 0; j < 4; ++j)
            acc[r][j] = (float4v){0.f, 0.f, 0.f, 0.f};

    // A: 2 sets, ROLLING per-rb refill (slot refilled for kt+2 immediately
    // after its last MFMA read -> WAR-pinned, no extra regs, ~1.5-2kt cover).
    // B: 3 sets (distance 3). Fully unrolled -> all indices static.
    short8 as[2][7], bs[3][4];
#pragma unroll
    for (int r = 0; r < 7; ++r) { LOADA_RB(as[0][r], r, 0) }
#pragma unroll
    for (int r = 0; r < 7; ++r) { LOADA_RB(as[1][r], r, 1) }
    LOADB(bs[0], 0)
    LOADB(bs[1], 1)
    LOADB(bs[2], 2)

#pragma unroll
    for (int kt = 0; kt < NKT; ++kt) {
        const int ai = kt & 1;
        const int bi = kt % 3;
#pragma unroll
        for (int r = 0; r < 7; ++r) {
            __builtin_amdgcn_s_setprio(1);
#pragma unroll
            for (int j = 0; j < 4; ++j)
                acc[r][j] = __builtin_amdgcn_mfma_f32_16x16x32_bf16(
                    as[ai][r], bs[bi][j], acc[r][j], 0, 0, 0);
            __builtin_amdgcn_s_setprio(0);
            if (kt + 2 < NKT) { LOADA_RB(as[ai][r], r, kt + 2) }
        }
        if (kt + 3 < NKT) LOADB(bs[bi], kt + 3)
    }

    // ---- in-register top-3 over this wave's 112 rows, per owned column ----
    // rows r*64 + w*16 + quad*4 + g; only r==6 can exceed HW=441 (static).
    float T0[4], T1[4], T2[4];
#pragma unroll
    for (int j = 0; j < 4; ++j) { T0[j] = -1e30f; T1[j] = -1e30f; T2[j] = -1e30f; }
#pragma unroll
    for (int r = 0; r < 7; ++r)
#pragma unroll
        for (int j = 0; j < 4; ++j)
#pragma unroll
            for (int g = 0; g < 4; ++g) {
                float v = acc[r][j][g];
                if (r == 6) {
                    int row = 384 + w * 16 + quad * 4 + g;
                    if (row >= HW) v = -1e30f;
                }
                ins3(T0[j], T1[j], T2[j], v);
            }

    // quad-butterfly merge (rows spread over lane bits 4,5)
#pragma unroll
    for (int j = 0; j < 4; ++j) {
#pragma unroll
        for (int d = 16; d <= 32; d <<= 1) {
            float o0 = __shfl_xor(T0[j], d, 64);
            float o1 = __shfl_xor(T1[j], d, 64);
            float o2 = __shfl_xor(T2[j], d, 64);
            ins3(T0[j], T1[j], T2[j], o0);
            ins3(T0[j], T1[j], T2[j], o1);
            ins3(T0[j], T1[j], T2[j], o2);
        }
    }

    // cross-wave merge via LDS
    if (quad == 0) {
#pragma unroll
        for (int j = 0; j < 4; ++j) {
            mrg[w][j * 16 + c16][0] = T0[j];
            mrg[w][j * 16 + c16][1] = T1[j];
            mrg[w][j * 16 + c16][2] = T2[j];
        }
    }
    __syncthreads();
    if (tid < 64) {
        int col = tid;
        float t0 = mrg[0][col][0], t1 = mrg[0][col][1], t2 = mrg[0][col][2];
#pragma unroll
        for (int ww = 1; ww < 4; ++ww) {
            ins3(t0, t1, t2, mrg[ww][col][0]);
            ins3(t0, t1, t2, mrg[ww][col][1]);
            ins3(t0, t1, t2, mrg[ww][col][2]);
        }
        float s = (mt * 64 + col < HW) ? (t0 + t1 + t2) : 0.f;
#pragma unroll
        for (int d = 32; d >= 1; d >>= 1) s += __shfl_xor(s, d, 64);
        if (tid == 0) atomicAdd(&out[b * N_CLS + n], s);
    }
}

extern "C" void kernel_launch(void* const* d_in, const int* in_sizes, int n_in,
                              void* d_out, int out_size, void* d_ws, size_t ws_size,
                              hipStream_t stream) {
    const float* q = (const float*)d_in[0];
    const float* S = (const float*)d_in[1];
    float* out = (float*)d_out;

    char* ws = (char*)d_ws;
    size_t off = 0;
    __hip_bfloat16* qn2 = (__hip_bfloat16*)(ws + off);
    off += (size_t)B_IMGS * NRB * NKT * CHUNK * 2;  off = (off + 255) & ~(size_t)255;
    __hip_bfloat16* sn2 = (__hip_bfloat16*)(ws + off);

    // 2 dispatches total: fused prep (also zeroes out) -> gemm
    prep_kernel<<<dim3(80 * 7), dim3(256), 0, stream>>>(q, S, qn2, sn2, out);
    // 8 XCD groups x 350 slots (35 blocks/image); b>=75 slots exit immediately
    gemm_top3_kernel<<<dim3(8 * 350), dim3(256), 0, stream>>>(qn2, sn2, out);
}

// Round 12
// 252.799 us; speedup vs baseline: 1.2311x; 1.0121x over previous
//
#include <hip/hip_runtime.h>
#include <hip/hip_bf16.h>

// KNN_itc: out[b][n] = sum over support descriptors m (441) of top-3 (over 441
// query descriptors) cosine similarities, C=640, bf16 MFMA.
//
// R17 (vs R16 = gemm 104.2us w/ 18MB scratch spill, total 255.9):
//  - R16 won (113.6 -> 104.2: rolling per-rb A refill + setprio + B dist-3)
//    but VGPR pinned at 128 and spilled (WRITE_SIZE 82KB -> 18.4MB). Register
//    arithmetic: acc 112 AGPR + A 2x28 + B 3x16 = 216 + addr/misc ~ 240+ ->
//    no allocator slack. R17: B sets 3 -> 2 (dist-2, ~225 total regs, slack
//    restored). Everything else identical.
//  - Tripwires: VGPR_Count <= 124, WRITE_SIZE == 82KB, FETCH ~45MB.
//  - Context: non-gemm ~150us is harness-fixed (re-poison train; dispatch
//    fusion R13 moved it only 8us). gemm floor: 2.31GB L2 traffic = 67us;
//    at 104 we're at 64% utilization. All LDS/barrier structures (R6/7/8/14)
//    and register-depth/occupancy variants (R10/11/15) empirically refuted.
//  - prep UNCHANGED from R13.

#define B_IMGS 75
#define N_CLS  5
#define C_DIM  640
#define HW     441
#define HWP    448
#define NKT    20            // 640 / 32 k-chunks
#define NRB    28            // 448 / 16 row-blocks per image
#define CHUNK  512           // 16 rows x 32 k elems = 1 KiB

typedef __attribute__((ext_vector_type(8))) short  short8;   // 8 x bf16
typedef __attribute__((ext_vector_type(4))) float  float4v;  // MFMA acc

__device__ __forceinline__ void ins3(float& t0, float& t1, float& t2, float v) {
    float m  = fminf(t0, v);
    t0 = fmaxf(t0, v);
    float m2 = fminf(t1, m);
    t1 = fmaxf(t1, m);
    t2 = fmaxf(t2, m2);
}

// ---- fused prep: sumsq + normalize + bf16 + fragment-linear pack ----
// block=(img 0..79, h0 0..6); 560 blocks x 256 thr
// chunk layout: elem(row=r16, k32) at oct*128 + r16*8 + (k32&7), oct=k32>>3
//   -> gemm lane l reads elems [l*8, l*8+8): row=l&15, k32=(l>>4)*8+j (MFMA frag)
__global__ __launch_bounds__(256)
void prep_kernel(const float* __restrict__ q, const float* __restrict__ S,
                 __hip_bfloat16* __restrict__ qn2, __hip_bfloat16* __restrict__ sn2,
                 float* __restrict__ out) {
    __shared__ float part[4][64];
    __shared__ float inv[64];

    int bid = blockIdx.x;
    // zero the output accumulator (replaces the hipMemsetAsync dispatch);
    // gemm is a later dispatch on the same stream -> ordering is safe.
    if (bid == 0) {
        for (int i = threadIdx.x; i < B_IMGS * N_CLS; i += 256) out[i] = 0.f;
    }

    int img = bid / 7;               // 0..79 (0..74 = q, 75..79 = S)
    int h0  = bid % 7;
    const float* src; __hip_bfloat16* dst;
    if (img < B_IMGS) {
        src = q + (size_t)img * C_DIM * HW;
        dst = qn2 + (size_t)img * NRB * NKT * CHUNK;
    } else {
        src = S + (size_t)(img - B_IMGS) * C_DIM * HW;
        dst = sn2 + (size_t)(img - B_IMGS) * NRB * NKT * CHUNK;
    }
    int t  = threadIdx.x;
    int hl = t & 63;
    int p  = t >> 6;                 // wave id / 160-channel slice
    int hw = h0 * 64 + hl;
    int hwc = (hw < HW) ? hw : (HW - 1);

    // ---- pass 1: sum of squares over C (coalesced, 16-deep batches) ----
    float ss = 0.f;
    for (int c0 = p * 160; c0 < (p + 1) * 160; c0 += 16) {
        float v[16];
#pragma unroll
        for (int j = 0; j < 16; ++j) v[j] = src[(size_t)(c0 + j) * HW + hwc];
#pragma unroll
        for (int j = 0; j < 16; ++j) ss += v[j] * v[j];
    }
    part[p][hl] = ss;
    __syncthreads();
    if (t < 64) {
        float tot = part[0][t] + part[1][t] + part[2][t] + part[3][t];
        // pad rows (hw>=441) -> 0 so packed pad descriptors are zeros
        inv[t] = (h0 * 64 + t < HW) ? rsqrtf(tot) : 0.f;
    }
    __syncthreads();

    // ---- pass 2: L2/L3-hot re-read, scale, pack in registers, store ----
    // wave p owns chunk rb = h0*4+p; lane tl writes bytes [tl*16, tl*16+16)
    int tl  = hl;
    int row = tl & 15;
    int oct = tl >> 4;
    int rb  = h0 * 4 + p;
    int hw2 = h0 * 64 + p * 16 + row;
    int hw2c = (hw2 < HW) ? hw2 : (HW - 1);
    float iv = inv[p * 16 + row];    // 0 for pad rows
    const float* s2 = src + hw2c;
#pragma unroll 2
    for (int kt = 0; kt < NKT; ++kt) {
        float v[8];
#pragma unroll
        for (int j = 0; j < 8; ++j)
            v[j] = s2[(size_t)(kt * 32 + oct * 8 + j) * HW];
        short8 o;
#pragma unroll
        for (int j = 0; j < 8; ++j) {
            __hip_bfloat16 h = __float2bfloat16(v[j] * iv);
            o[j] = *(short*)&h;
        }
        *(short8*)(dst + ((size_t)rb * NKT + kt) * CHUNK + tl * 8) = o;
    }
}

// ---- gemm + fused top-3: barrier-free all-register; rolling A, B dist-2 ----
#define LOADA_RB(dstv, r, kt)                                                   \
    dstv = *(const short8*)(pA + ((size_t)((r) * 4 + w) * NKT + (kt)) * CHUNK);

#define LOADB(bS, kt)                                                           \
    {                                                                           \
        _Pragma("unroll")                                                       \
        for (int j = 0; j < 4; ++j)                                             \
            bS[j] = *(const short8*)(pB + ((size_t)j * NKT + (kt)) * CHUNK);    \
    }

__global__ __launch_bounds__(256, 2)
void gemm_top3_kernel(const __hip_bfloat16* __restrict__ qn2,
                      const __hip_bfloat16* __restrict__ sn2,
                      float* __restrict__ out) {
    __shared__ float mrg[4][64][3];

    // XCD-grouping swizzle: all 35 (n,mt) blocks of image b on one XCD
    int id  = blockIdx.x;
    int xcd = id & 7;
    int j8  = id >> 3;
    int b   = (j8 / 35) * 8 + xcd;
    if (b >= B_IMGS) return;
    int inner = j8 % 35;
    int n  = inner / 7;
    int mt = inner % 7;

    int tid  = threadIdx.x;
    int w    = tid >> 6;
    int lane = tid & 63;
    int c16  = lane & 15;
    int quad = lane >> 4;

    // fragment base: lane l owns bytes [l*16, l*16+16) of each 1KiB chunk
    const __hip_bfloat16* pA = qn2 + (size_t)b * NRB * NKT * CHUNK + lane * 8;
    const __hip_bfloat16* pB = sn2 + ((size_t)n * NRB + mt * 4) * NKT * CHUNK + lane * 8;

    float4v acc[7][4];
#pragma unroll
    for (int r = 0; r < 7; ++r)
#pragma unroll
        for (int j = 0; j < 4; ++j)
            acc[r][j] = (float4v){0.f, 0.f, 0.f, 0.f};

    // A: 2 sets, ROLLING per-rb refill (slot refilled for kt+2 immediately
    // after its last MFMA read -> WAR-pinned, no extra regs, ~1.5-2kt cover).
    // B: 2 sets (distance 2). Fully unrolled -> all indices static.
    short8 as[2][7], bs[2][4];
#pragma unroll
    for (int r = 0; r < 7; ++r) { LOADA_RB(as[0][r], r, 0) }
#pragma unroll
    for (int r = 0; r < 7; ++r) { LOADA_RB(as[1][r], r, 1) }
    LOADB(bs[0], 0)
    LOADB(bs[1], 1)

#pragma unroll
    for (int kt = 0; kt < NKT; ++kt) {
        const int ai = kt & 1;
#pragma unroll
        for (int r = 0; r < 7; ++r) {
            __builtin_amdgcn_s_setprio(1);
#pragma unroll
            for (int j = 0; j < 4; ++j)
                acc[r][j] = __builtin_amdgcn_mfma_f32_16x16x32_bf16(
                    as[ai][r], bs[ai][j], acc[r][j], 0, 0, 0);
            __builtin_amdgcn_s_setprio(0);
            if (kt + 2 < NKT) { LOADA_RB(as[ai][r], r, kt + 2) }
        }
        if (kt + 2 < NKT) LOADB(bs[ai], kt + 2)
    }

    // ---- in-register top-3 over this wave's 112 rows, per owned column ----
    // rows r*64 + w*16 + quad*4 + g; only r==6 can exceed HW=441 (static).
    float T0[4], T1[4], T2[4];
#pragma unroll
    for (int j = 0; j < 4; ++j) { T0[j] = -1e30f; T1[j] = -1e30f; T2[j] = -1e30f; }
#pragma unroll
    for (int r = 0; r < 7; ++r)
#pragma unroll
        for (int j = 0; j < 4; ++j)
#pragma unroll
            for (int g = 0; g < 4; ++g) {
                float v = acc[r][j][g];
                if (r == 6) {
                    int row = 384 + w * 16 + quad * 4 + g;
                    if (row >= HW) v = -1e30f;
                }
                ins3(T0[j], T1[j], T2[j], v);
            }

    // quad-butterfly merge (rows spread over lane bits 4,5)
#pragma unroll
    for (int j = 0; j < 4; ++j) {
#pragma unroll
        for (int d = 16; d <= 32; d <<= 1) {
            float o0 = __shfl_xor(T0[j], d, 64);
            float o1 = __shfl_xor(T1[j], d, 64);
            float o2 = __shfl_xor(T2[j], d, 64);
            ins3(T0[j], T1[j], T2[j], o0);
            ins3(T0[j], T1[j], T2[j], o1);
            ins3(T0[j], T1[j], T2[j], o2);
        }
    }

    // cross-wave merge via LDS
    if (quad == 0) {
#pragma unroll
        for (int j = 0; j < 4; ++j) {
            mrg[w][j * 16 + c16][0] = T0[j];
            mrg[w][j * 16 + c16][1] = T1[j];
            mrg[w][j * 16 + c16][2] = T2[j];
        }
    }
    __syncthreads();
    if (tid < 64) {
        int col = tid;
        float t0 = mrg[0][col][0], t1 = mrg[0][col][1], t2 = mrg[0][col][2];
#pragma unroll
        for (int ww = 1; ww < 4; ++ww) {
            ins3(t0, t1, t2, mrg[ww][col][0]);
            ins3(t0, t1, t2, mrg[ww][col][1]);
            ins3(t0, t1, t2, mrg[ww][col][2]);
        }
        float s = (mt * 64 + col < HW) ? (t0 + t1 + t2) : 0.f;
#pragma unroll
        for (int d = 32; d >= 1; d >>= 1) s += __shfl_xor(s, d, 64);
        if (tid == 0) atomicAdd(&out[b * N_CLS + n], s);
    }
}

extern "C" void kernel_launch(void* const* d_in, const int* in_sizes, int n_in,
                              void* d_out, int out_size, void* d_ws, size_t ws_size,
                              hipStream_t stream) {
    const float* q = (const float*)d_in[0];
    const float* S = (const float*)d_in[1];
    float* out = (float*)d_out;

    char* ws = (char*)d_ws;
    size_t off = 0;
    __hip_bfloat16* qn2 = (__hip_bfloat16*)(ws + off);
    off += (size_t)B_IMGS * NRB * NKT * CHUNK * 2;  off = (off + 255) & ~(size_t)255;
    __hip_bfloat16* sn2 = (__hip_bfloat16*)(ws + off);

    // 2 dispatches total: fused prep (also zeroes out) -> gemm
    prep_kernel<<<dim3(80 * 7), dim3(256), 0, stream>>>(q, S, qn2, sn2, out);
    // 8 XCD groups x 350 slots (35 blocks/image); b>=75 slots exit immediately
    gemm_top3_kernel<<<dim3(8 * 350), dim3(256), 0, stream>>>(qn2, sn2, out);
}

// Round 13
// 240.171 us; speedup vs baseline: 1.2958x; 1.0526x over previous
//
#include <hip/hip_runtime.h>
#include <hip/hip_bf16.h>

// KNN_itc: out[b][n] = sum over support descriptors m (441) of top-3 (over 441
// query descriptors) cosine similarities, C=640, bf16 MFMA.
//
// R18 (vs R17 = gemm 100.4us / total 252.8):
//  - DEFERRED NORMALIZATION. sim = invs[col] * top3_row(acc * invq[row]) --
//    invs>0 is column-constant (ordering preserved); invq applied pre-top3 in
//    the gemm epilogue. This lets prep pack RAW bf16 in a SINGLE pass:
//    sumsq accumulates from the same registers being packed (oct-wise
//    shfl_xor(16,32) reduce, lane oct==0 stores invn). Prep global reads
//    180MB -> 90MB; zero LDS, zero barriers in prep.
//  - gemm = R17 skeleton (barrier-free all-register, rolling A dist-2,
//    B dist-2, setprio) + epilogue: invr[7] as float4 loads from invn
//    (L2-resident 448 floats/image), v = acc*invr before ins3; invs applied
//    once per column in the final reduce. Pad rows/cols still masked (raw
//    garbage in pads is finite and masked exactly as before).
//  - Rounding profile unchanged (one bf16 rounding of operand, fp32 norms):
//    absmax expected ~1.0 as before.
//  - Tripwires: VGPR <= ~132, WRITE_SIZE == 82KB, absmax <= 2.88.

#define B_IMGS 75
#define N_CLS  5
#define C_DIM  640
#define HW     441
#define HWP    448
#define NKT    20            // 640 / 32 k-chunks
#define NRB    28            // 448 / 16 row-blocks per image
#define CHUNK  512           // 16 rows x 32 k elems = 1 KiB

typedef __attribute__((ext_vector_type(8))) short  short8;   // 8 x bf16
typedef __attribute__((ext_vector_type(4))) float  float4v;  // MFMA acc / f32x4

__device__ __forceinline__ void ins3(float& t0, float& t1, float& t2, float v) {
    float m  = fminf(t0, v);
    t0 = fmaxf(t0, v);
    float m2 = fminf(t1, m);
    t1 = fmaxf(t1, m);
    t2 = fmaxf(t2, m2);
}

// ---- single-pass prep: pack raw bf16 + fused sumsq -> invn ----
// block=(img 0..79, h0 0..6); 560 blocks x 256 thr; no LDS, no barriers.
// wave p owns chunk rb=h0*4+p; lane (row=tl&15, oct=tl>>4) packs its fragment
// bytes [tl*16,tl*16+16) per kt while accumulating sumsq of its c-slice;
// oct-reduce via shfl_xor(16,32) completes the row's sum over all 640 c.
__global__ __launch_bounds__(256)
void prep_kernel(const float* __restrict__ q, const float* __restrict__ S,
                 __hip_bfloat16* __restrict__ qn2, __hip_bfloat16* __restrict__ sn2,
                 float* __restrict__ invn, float* __restrict__ out) {
    int bid = blockIdx.x;
    // zero the output accumulator (replaces hipMemsetAsync; stream-ordered)
    if (bid == 0) {
        for (int i = threadIdx.x; i < B_IMGS * N_CLS; i += 256) out[i] = 0.f;
    }

    int img = bid / 7;               // 0..79 (0..74 = q, 75..79 = S)
    int h0  = bid % 7;
    const float* src; __hip_bfloat16* dst;
    if (img < B_IMGS) {
        src = q + (size_t)img * C_DIM * HW;
        dst = qn2 + (size_t)img * NRB * NKT * CHUNK;
    } else {
        src = S + (size_t)(img - B_IMGS) * C_DIM * HW;
        dst = sn2 + (size_t)(img - B_IMGS) * NRB * NKT * CHUNK;
    }
    int t   = threadIdx.x;
    int tl  = t & 63;
    int p   = t >> 6;                // wave id -> chunk rb
    int row = tl & 15;
    int oct = tl >> 4;
    int rb  = h0 * 4 + p;
    int hw2 = h0 * 64 + p * 16 + row;
    int hwc = (hw2 < HW) ? hw2 : (HW - 1);   // pad rows read row 440 (masked later)
    const float* s2 = src + hwc;

    float ss = 0.f;
#pragma unroll 2
    for (int kt = 0; kt < NKT; ++kt) {
        float v[8];
#pragma unroll
        for (int j = 0; j < 8; ++j)
            v[j] = s2[(size_t)(kt * 32 + oct * 8 + j) * HW];
        short8 o;
#pragma unroll
        for (int j = 0; j < 8; ++j) {
            ss += v[j] * v[j];
            __hip_bfloat16 h = __float2bfloat16(v[j]);   // RAW bf16 (norm deferred)
            o[j] = *(short*)&h;
        }
        *(short8*)(dst + ((size_t)rb * NKT + kt) * CHUNK + tl * 8) = o;
    }
    // complete row sumsq across the 4 octs (lanes row, row+16, row+32, row+48)
    ss += __shfl_xor(ss, 16, 64);
    ss += __shfl_xor(ss, 32, 64);
    if (oct == 0)
        invn[img * HWP + hw2] = (hw2 < HW) ? rsqrtf(ss) : 0.f;
}

// ---- gemm + fused top-3: barrier-free all-register; rolling A, B dist-2 ----
#define LOADA_RB(dstv, r, kt)                                                   \
    dstv = *(const short8*)(pA + ((size_t)((r) * 4 + w) * NKT + (kt)) * CHUNK);

#define LOADB(bS, kt)                                                           \
    {                                                                           \
        _Pragma("unroll")                                                       \
        for (int j = 0; j < 4; ++j)                                             \
            bS[j] = *(const short8*)(pB + ((size_t)j * NKT + (kt)) * CHUNK);    \
    }

__global__ __launch_bounds__(256, 2)
void gemm_top3_kernel(const __hip_bfloat16* __restrict__ qn2,
                      const __hip_bfloat16* __restrict__ sn2,
                      const float* __restrict__ invn,
                      float* __restrict__ out) {
    __shared__ float mrg[4][64][3];

    // XCD-grouping swizzle: all 35 (n,mt) blocks of image b on one XCD
    int id  = blockIdx.x;
    int xcd = id & 7;
    int j8  = id >> 3;
    int b   = (j8 / 35) * 8 + xcd;
    if (b >= B_IMGS) return;
    int inner = j8 % 35;
    int n  = inner / 7;
    int mt = inner % 7;

    int tid  = threadIdx.x;
    int w    = tid >> 6;
    int lane = tid & 63;
    int c16  = lane & 15;
    int quad = lane >> 4;

    // fragment base: lane l owns bytes [l*16, l*16+16) of each 1KiB chunk
    const __hip_bfloat16* pA = qn2 + (size_t)b * NRB * NKT * CHUNK + lane * 8;
    const __hip_bfloat16* pB = sn2 + ((size_t)n * NRB + mt * 4) * NKT * CHUNK + lane * 8;

    float4v acc[7][4];
#pragma unroll
    for (int r = 0; r < 7; ++r)
#pragma unroll
        for (int j = 0; j < 4; ++j)
            acc[r][j] = (float4v){0.f, 0.f, 0.f, 0.f};

    // A: 2 sets, ROLLING per-rb refill; B: 2 sets (distance 2). Fully unrolled.
    short8 as[2][7], bs[2][4];
#pragma unroll
    for (int r = 0; r < 7; ++r) { LOADA_RB(as[0][r], r, 0) }
#pragma unroll
    for (int r = 0; r < 7; ++r) { LOADA_RB(as[1][r], r, 1) }
    LOADB(bs[0], 0)
    LOADB(bs[1], 1)

#pragma unroll
    for (int kt = 0; kt < NKT; ++kt) {
        const int ai = kt & 1;
#pragma unroll
        for (int r = 0; r < 7; ++r) {
            __builtin_amdgcn_s_setprio(1);
#pragma unroll
            for (int j = 0; j < 4; ++j)
                acc[r][j] = __builtin_amdgcn_mfma_f32_16x16x32_bf16(
                    as[ai][r], bs[ai][j], acc[r][j], 0, 0, 0);
            __builtin_amdgcn_s_setprio(0);
            if (kt + 2 < NKT) { LOADA_RB(as[ai][r], r, kt + 2) }
        }
        if (kt + 2 < NKT) LOADB(bs[ai], kt + 2)
    }

    // ---- epilogue: apply invq[row], then in-register top-3 ----
    // lane's rows: r*64 + w*16 + quad*4 + g -> 7 aligned float4 loads of invn.
    float4v invr[7];
#pragma unroll
    for (int r = 0; r < 7; ++r)
        invr[r] = *(const float4v*)(invn + (size_t)b * HWP + r * 64 + w * 16 + quad * 4);

    float T0[4], T1[4], T2[4];
#pragma unroll
    for (int j = 0; j < 4; ++j) { T0[j] = -1e30f; T1[j] = -1e30f; T2[j] = -1e30f; }
#pragma unroll
    for (int r = 0; r < 7; ++r)
#pragma unroll
        for (int j = 0; j < 4; ++j)
#pragma unroll
            for (int g = 0; g < 4; ++g) {
                float v = acc[r][j][g] * invr[r][g];
                if (r == 6) {                     // only r==6 rows can pad
                    int row = 384 + w * 16 + quad * 4 + g;
                    if (row >= HW) v = -1e30f;
                }
                ins3(T0[j], T1[j], T2[j], v);
            }

    // quad-butterfly merge (rows spread over lane bits 4,5)
#pragma unroll
    for (int j = 0; j < 4; ++j) {
#pragma unroll
        for (int d = 16; d <= 32; d <<= 1) {
            float o0 = __shfl_xor(T0[j], d, 64);
            float o1 = __shfl_xor(T1[j], d, 64);
            float o2 = __shfl_xor(T2[j], d, 64);
            ins3(T0[j], T1[j], T2[j], o0);
            ins3(T0[j], T1[j], T2[j], o1);
            ins3(T0[j], T1[j], T2[j], o2);
        }
    }

    // cross-wave merge via LDS
    if (quad == 0) {
#pragma unroll
        for (int j = 0; j < 4; ++j) {
            mrg[w][j * 16 + c16][0] = T0[j];
            mrg[w][j * 16 + c16][1] = T1[j];
            mrg[w][j * 16 + c16][2] = T2[j];
        }
    }
    __syncthreads();
    if (tid < 64) {
        int col = tid;
        float t0 = mrg[0][col][0], t1 = mrg[0][col][1], t2 = mrg[0][col][2];
#pragma unroll
        for (int ww = 1; ww < 4; ++ww) {
            ins3(t0, t1, t2, mrg[ww][col][0]);
            ins3(t0, t1, t2, mrg[ww][col][1]);
            ins3(t0, t1, t2, mrg[ww][col][2]);
        }
        // apply the column-constant support norm AFTER top-3 (ordering-safe)
        float invs_c = invn[(size_t)(B_IMGS + n) * HWP + mt * 64 + col];
        float s = (mt * 64 + col < HW) ? (t0 + t1 + t2) * invs_c : 0.f;
#pragma unroll
        for (int d = 32; d >= 1; d >>= 1) s += __shfl_xor(s, d, 64);
        if (tid == 0) atomicAdd(&out[b * N_CLS + n], s);
    }
}

extern "C" void kernel_launch(void* const* d_in, const int* in_sizes, int n_in,
                              void* d_out, int out_size, void* d_ws, size_t ws_size,
                              hipStream_t stream) {
    const float* q = (const float*)d_in[0];
    const float* S = (const float*)d_in[1];
    float* out = (float*)d_out;

    char* ws = (char*)d_ws;
    size_t off = 0;
    __hip_bfloat16* qn2 = (__hip_bfloat16*)(ws + off);
    off += (size_t)B_IMGS * NRB * NKT * CHUNK * 2;  off = (off + 255) & ~(size_t)255;
    __hip_bfloat16* sn2 = (__hip_bfloat16*)(ws + off);
    off += (size_t)N_CLS * NRB * NKT * CHUNK * 2;   off = (off + 255) & ~(size_t)255;
    float* invn = (float*)(ws + off);               // [80][448] norms

    // 2 dispatches: single-pass prep (also zeroes out) -> gemm
    prep_kernel<<<dim3(80 * 7), dim3(256), 0, stream>>>(q, S, qn2, sn2, invn, out);
    // 8 XCD groups x 350 slots (35 blocks/image); b>=75 slots exit immediately
    gemm_top3_kernel<<<dim3(8 * 350), dim3(256), 0, stream>>>(qn2, sn2, invn, out);
}